// Round 9
// baseline (86.873 us; speedup 1.0000x reference)
//
#include <hip/hip_runtime.h>

#define N_NODES 50000
#define N_EDGES 600000
#define DIM 128
#define NB 782                 // 64-node buckets (= gather blocks)
#define NJ 391                 // gemm/scatter blocks; 2 tiles or 1536 edges each
#define EPB 1536               // edges per partition block: 391*1536 = 600576
#define GCAP 2048              // gather LDS sort capacity (mean 767, sd 28)

typedef short bf16x8 __attribute__((ext_vector_type(8)));
typedef float f32x4 __attribute__((ext_vector_type(4)));

__device__ __forceinline__ float bf2f(unsigned short u) {
    union { unsigned int i; float f; } x; x.i = ((unsigned int)u) << 16; return x.f;
}
__device__ __forceinline__ unsigned short f2bf(float f) {
    union { float f; unsigned int i; } x; x.f = f;
    unsigned int r = x.i + 0x7FFFu + ((x.i >> 16) & 1u);   // RNE
    return (unsigned short)(r >> 16);
}

// ---------------- MFMA GEMM: 2 node-tiles/block sharing one W staging ----------------
// h[n][d] = bf16( sum_k x[n][k] * W[d][k] ). 512 threads = 8 waves: waves 0-3
// do tile 2*bid, waves 4-7 do tile 2*bid+1. Fused 64-node-bucket histogram
// (LDS atomics only) + zeroing of the scanAB done-counter.
__global__ __launch_bounds__(512) void gemm_kernel(const float* __restrict__ x,
                                                   const float* __restrict__ W,
                                                   unsigned short* __restrict__ h,
                                                   const int* __restrict__ rows,
                                                   unsigned short* __restrict__ Hm16,
                                                   int* __restrict__ done) {
    __shared__ unsigned char Wl[128 * 256];   // bf16[128 dims][128 k], swizzled
    __shared__ int cntL[NB];
    const int tid = threadIdx.x;

    if (Hm16) {
        for (int i = tid; i < NB; i += 512) cntL[i] = 0;
        if (blockIdx.x == 0 && tid == 0) *done = 0;    // reset last-block counter
    }

    // ---- stage W -> LDS bf16 (swizzled): 4096 float4 chunks, 8 per thread
#pragma unroll
    for (int i = 0; i < 8; ++i) {
        int c  = tid + i * 512;
        int od = c >> 5;
        int kg = c & 31;
        float4 w = *((const float4*)(W + od * DIM) + kg);
        unsigned int lo = (unsigned int)f2bf(w.x) | ((unsigned int)f2bf(w.y) << 16);
        unsigned int hi = (unsigned int)f2bf(w.z) | ((unsigned int)f2bf(w.w) << 16);
        int byte = od * 256 + ((kg * 8) ^ ((od & 7) << 4));
        *reinterpret_cast<uint2*>(Wl + byte) = make_uint2(lo, hi);
    }

    // ---- this wave's tile + node (node = lane&15, k-slot q = lane>>4)
    const int lane = tid & 63;
    const int w8   = tid >> 6;          // wave 0..7
    const int wv   = w8 & 3;            // wave-in-tile
    const int t    = blockIdx.x * 2 + (w8 >> 2);   // tile 0..781
    const int q    = lane >> 4;
    const int node = t * 64 + wv * 16 + (lane & 15);
    const int ncl  = node < N_NODES ? node : N_NODES - 1;

    bf16x8 xb[4];
#pragma unroll
    for (int s = 0; s < 4; ++s) {
        const float* xp = x + (size_t)ncl * DIM + s * 32 + q * 8;
        float4 x0 = *(const float4*)(xp);
        float4 x1 = *(const float4*)(xp + 4);
        bf16x8 v;
        v[0] = (short)f2bf(x0.x); v[1] = (short)f2bf(x0.y);
        v[2] = (short)f2bf(x0.z); v[3] = (short)f2bf(x0.w);
        v[4] = (short)f2bf(x1.x); v[5] = (short)f2bf(x1.y);
        v[6] = (short)f2bf(x1.z); v[7] = (short)f2bf(x1.w);
        xb[s] = v;
    }

    __syncthreads();   // cntL zeroed + W staged

    // ---- fused histogram: LDS atomics only (1536 edges/block)
    if (Hm16) {
        int ebase = blockIdx.x * EPB;
#pragma unroll
        for (int i = 0; i < 3; ++i) {
            int e = ebase + tid + i * 512;
            if (e < N_EDGES) atomicAdd(&cntL[rows[e] >> 6], 1);
        }
    }

    // ---- 8 dim-tiles x 4 k-steps of mfma_f32_16x16x32_bf16
#pragma unroll
    for (int dt = 0; dt < 8; ++dt) {
        f32x4 acc = {0.f, 0.f, 0.f, 0.f};
        const int od = dt * 16 + (lane & 15);
#pragma unroll
        for (int s = 0; s < 4; ++s) {
            int byte = od * 256 + ((s * 64 + q * 16) ^ ((od & 7) << 4));
            bf16x8 a = *reinterpret_cast<const bf16x8*>(Wl + byte);
            acc = __builtin_amdgcn_mfma_f32_16x16x32_bf16(a, xb[s], acc, 0, 0, 0);
        }
        if (node < N_NODES) {
            unsigned int lo = (unsigned int)f2bf(acc[0]) | ((unsigned int)f2bf(acc[1]) << 16);
            unsigned int hi = (unsigned int)f2bf(acc[2]) | ((unsigned int)f2bf(acc[3]) << 16);
            *reinterpret_cast<uint2*>(h + (size_t)node * DIM + dt * 16 + q * 4) = make_uint2(lo, hi);
        }
    }

    if (Hm16) {
        __syncthreads();
        unsigned short* Hrow = Hm16 + (size_t)blockIdx.x * NB;
        for (int i = tid; i < NB; i += 512) Hrow[i] = (unsigned short)cntL[i];
    }
}

// ---------------- scanAB: coalesced per-bucket scan along j + last-block scanB ----------------
// 13 blocks x 512 threads. Block g owns buckets g*64+lane. Two passes over the
// u16 Hm (lane-coalesced); LDS partials combine the 8 waves' j-chunks.
// Last block (atomic counter) scans bucket totals -> boff and resets the counter.
__global__ __launch_bounds__(512) void scanAB_kernel(unsigned short* __restrict__ Hm16,
                                                     int* __restrict__ tot,
                                                     int* __restrict__ boff,
                                                     int* __restrict__ done) {
    __shared__ int part[8 * 64];
    __shared__ int lastFlag;
    int tid = threadIdx.x, g = blockIdx.x;
    int w = tid >> 6, lane = tid & 63;
    int bucket = g * 64 + lane;
    bool bv = bucket < NB;
    int j0 = w * 49;
    int j1 = j0 + 49; if (j1 > NJ) j1 = NJ;

    // pass 1: per-(wave,bucket) partial sums
    int ps = 0;
    if (bv) for (int j = j0; j < j1; ++j) ps += Hm16[(size_t)j * NB + bucket];
    part[w * 64 + lane] = ps;
    __syncthreads();
    int base = 0, total = 0;
#pragma unroll
    for (int ww = 0; ww < 8; ++ww) {
        int p = part[ww * 64 + lane];
        if (ww < w) base += p;
        total += p;
    }
    if (w == 0 && bv) tot[bucket] = total;

    // pass 2: write exclusive prefix back (u16; max < bucket total ~900)
    if (bv) {
        int carry = base;
        for (int j = j0; j < j1; ++j) {
            size_t idx = (size_t)j * NB + bucket;
            int v = Hm16[idx];
            Hm16[idx] = (unsigned short)carry;
            carry += v;
        }
    }
    __syncthreads();
    if (tid == 0) {
        __threadfence();
        int old = atomicAdd(done, 1);
        lastFlag = (old == (int)gridDim.x - 1) ? 1 : 0;
    }
    __syncthreads();
    if (lastFlag) {
        __threadfence();   // acquire other blocks' tot writes
        if (tid < 64) {
            int carry = 0;
            for (int ch = 0; ch < 13; ++ch) {
                int i = ch * 64 + tid;
                int v = (i < NB) ? tot[i] : 0;
                int incl = v;
#pragma unroll
                for (int d = 1; d < 64; d <<= 1) {
                    int t = __shfl_up(incl, d);
                    if (tid >= d) incl += t;
                }
                if (i < NB) boff[i] = carry + incl - v;
                carry += __shfl(incl, 63);
            }
            if (tid == 0) { boff[NB] = N_EDGES; *done = 0; }
        }
    }
}

// ---------------- scatter: deterministic bucket partition, LDS cursors ----------------
__global__ __launch_bounds__(512) void scatter_kernel(const int* __restrict__ rows,
                                                      const int* __restrict__ cols,
                                                      const float* __restrict__ vals,
                                                      const unsigned short* __restrict__ Hm16,
                                                      const int* __restrict__ boff,
                                                      int2* __restrict__ erec) {
    __shared__ int cl[NB];
    int tid = threadIdx.x, j = blockIdx.x;
    const unsigned short* Hrow = Hm16 + (size_t)j * NB;
    for (int i = tid; i < NB; i += 512) cl[i] = boff[i] + (int)Hrow[i];
    __syncthreads();
    int ebase = j * EPB;
#pragma unroll
    for (int i = 0; i < 3; ++i) {
        int e = ebase + tid + i * 512;
        if (e < N_EDGES) {
            int r = rows[e];
            int slot = atomicAdd(&cl[r >> 6], 1);
            int2 rec;
            rec.x = cols[e] | ((r & 63) << 16);
            rec.y = __float_as_int(vals[e]);
            erec[slot] = rec;
        }
    }
}

// ---------------- gather: LDS counting sort + 8-node INTERLEAVED register accumulate ----------------
// 512 threads, 8 waves, 8 nodes/wave. Each wave walks its 8 nodes' edge
// streams simultaneously (wave-uniform cursors) -> 8 independent h-loads in
// flight per step regardless of node degree. Half-waves split each stream
// (stride 2); cross-half combine via shfl_xor(32). Fused ReLU.
__global__ __launch_bounds__(512) void gather_kernel(const unsigned short* __restrict__ h,
                                                     const int2* __restrict__ erec,
                                                     const int* __restrict__ boff,
                                                     float* __restrict__ out) {
    __shared__ int2 srt[GCAP];            // 16 KB sorted records
    __shared__ int hist[64];
    __shared__ int cursor[64];
    __shared__ int starts[65];
    int tid = threadIdx.x, b = blockIdx.x;
    int beg = boff[b], end = boff[b + 1];
    int cnt = end - beg;
    int w = tid >> 6, lane = tid & 63;
    int pos = lane & 31;                  // dim group: dims pos*4 .. pos*4+3
    int half = lane >> 5;

    if (tid < 64) hist[tid] = 0;
    __syncthreads();

    if (cnt <= GCAP) {
        // ---- phase 1: stage to registers + 64-bin histogram
        int2 rec[4];
        int  rr[4];
#pragma unroll
        for (int k = 0; k < 4; ++k) {
            int i = tid + k * 512;
            if (i < cnt) {
                rec[k] = erec[beg + i];
                rr[k] = (rec[k].x >> 16) & 63;
                atomicAdd(&hist[rr[k]], 1);
            }
        }
        __syncthreads();
        // ---- phase 2: exclusive scan of the 64 bins (wave 0)
        if (tid < 64) {
            int v = hist[tid], incl = v;
#pragma unroll
            for (int d = 1; d < 64; d <<= 1) {
                int t = __shfl_up(incl, d);
                if (tid >= d) incl += t;
            }
            starts[tid] = incl - v;
            cursor[tid] = incl - v;
            if (tid == 63) starts[64] = incl;
        }
        __syncthreads();
        // ---- phase 3: place into sorted LDS order
#pragma unroll
        for (int k = 0; k < 4; ++k) {
            int i = tid + k * 512;
            if (i < cnt) {
                int p2 = atomicAdd(&cursor[rr[k]], 1);
                srt[p2] = rec[k];
            }
        }
        __syncthreads();
        // ---- phase 4: 8 interleaved node streams per wave
        float4 acc[8];
        int curn[8], endn[8];
#pragma unroll
        for (int n = 0; n < 8; ++n) {
            int t = w * 8 + n;
            curn[n] = starts[t] + half;
            endn[n] = starts[t + 1];
            acc[n] = make_float4(0.f, 0.f, 0.f, 0.f);
        }
        bool more = (w * 8 < 64);
        while (more) {
            more = false;
            int2 r[8];
            bool act[8];
#pragma unroll
            for (int n = 0; n < 8; ++n) {
                act[n] = curn[n] < endn[n];
                r[n] = act[n] ? srt[curn[n]] : make_int2(0, 0);
            }
            ushort4 hv[8];
#pragma unroll
            for (int n = 0; n < 8; ++n) {
                hv[n] = act[n] ? *((const ushort4*)(h + (size_t)(r[n].x & 0xFFFF) * DIM) + pos)
                               : make_ushort4(0, 0, 0, 0);
            }
#pragma unroll
            for (int n = 0; n < 8; ++n) {
                if (act[n]) {
                    float v = __int_as_float(r[n].y);
                    acc[n].x += v * bf2f(hv[n].x);
                    acc[n].y += v * bf2f(hv[n].y);
                    acc[n].z += v * bf2f(hv[n].z);
                    acc[n].w += v * bf2f(hv[n].w);
                    curn[n] += 2;
                    if (curn[n] < endn[n]) more = true;
                }
            }
        }
        // ---- combine halves + store
#pragma unroll
        for (int n = 0; n < 8; ++n) {
            int node = b * 64 + w * 8 + n;
            float a0 = acc[n].x, a1 = acc[n].y, a2 = acc[n].z, a3 = acc[n].w;
            a0 += __shfl_xor(a0, 32);
            a1 += __shfl_xor(a1, 32);
            a2 += __shfl_xor(a2, 32);
            a3 += __shfl_xor(a3, 32);
            if (half == 0 && node < N_NODES) {
                float4 o;
                o.x = fmaxf(a0, 0.f);
                o.y = fmaxf(a1, 0.f);
                o.z = fmaxf(a2, 0.f);
                o.w = fmaxf(a3, 0.f);
                *reinterpret_cast<float4*>(&out[(size_t)node * DIM + pos * 4]) = o;
            }
        }
    } else {
        // ---- oversize-bucket fallback (statistically unreachable, kept for correctness)
        for (int t0 = 0; t0 < 8; ++t0) {
            int t = w * 8 + t0;
            int node = b * 64 + t;
            float a0 = 0.f, a1 = 0.f, a2 = 0.f, a3 = 0.f;
            for (int i = half; i < cnt; i += 2) {
                int2 r = erec[beg + i];
                if (((r.x >> 16) & 63) == t) {
                    ushort4 hv = *((const ushort4*)(h + (size_t)(r.x & 0xFFFF) * DIM) + pos);
                    float v = __int_as_float(r.y);
                    a0 += v * bf2f(hv.x);
                    a1 += v * bf2f(hv.y);
                    a2 += v * bf2f(hv.z);
                    a3 += v * bf2f(hv.w);
                }
            }
            a0 += __shfl_xor(a0, 32);
            a1 += __shfl_xor(a1, 32);
            a2 += __shfl_xor(a2, 32);
            a3 += __shfl_xor(a3, 32);
            if (half == 0 && node < N_NODES) {
                float4 o;
                o.x = fmaxf(a0, 0.f);
                o.y = fmaxf(a1, 0.f);
                o.z = fmaxf(a2, 0.f);
                o.w = fmaxf(a3, 0.f);
                *reinterpret_cast<float4*>(&out[(size_t)node * DIM + pos * 4]) = o;
            }
        }
    }
}

// ---------------- fallback: atomic scatter over bf16 h ----------------
__global__ __launch_bounds__(256) void edge_kernel(const unsigned short* __restrict__ h,
                                                   const float* __restrict__ vals,
                                                   const int* __restrict__ rows,
                                                   const int* __restrict__ cols,
                                                   float* __restrict__ out) {
    long long gid = (long long)blockIdx.x * 256 + threadIdx.x;
    int e    = (int)(gid >> 5);
    int lane = (int)(gid & 31);
    if (e >= N_EDGES) return;
    int r = rows[e];
    int c = cols[e];
    float v = vals[e];
    ushort4 hv = *((const ushort4*)(h + (size_t)c * DIM) + lane);
    float* op = &out[(size_t)r * DIM + lane * 4];
    atomicAdd(op + 0, v * bf2f(hv.x));
    atomicAdd(op + 1, v * bf2f(hv.y));
    atomicAdd(op + 2, v * bf2f(hv.z));
    atomicAdd(op + 3, v * bf2f(hv.w));
}

__global__ __launch_bounds__(256) void relu_kernel(float* __restrict__ out) {
    int i = blockIdx.x * 256 + threadIdx.x;
    float4* p = reinterpret_cast<float4*>(out) + i;
    float4 v = *p;
    v.x = fmaxf(v.x, 0.f);
    v.y = fmaxf(v.y, 0.f);
    v.z = fmaxf(v.z, 0.f);
    v.w = fmaxf(v.w, 0.f);
    *p = v;
}

extern "C" void kernel_launch(void* const* d_in, const int* in_sizes, int n_in,
                              void* d_out, int out_size, void* d_ws, size_t ws_size,
                              hipStream_t stream) {
    const float* x    = (const float*)d_in[0];
    const float* W    = (const float*)d_in[1];
    const float* vals = (const float*)d_in[2];
    const int*   rows = (const int*)d_in[3];
    const int*   cols = (const int*)d_in[4];
    float* out = (float*)d_out;

    // ---- workspace layout ----
    unsigned short* h = (unsigned short*)d_ws;                    // 12.8 MB bf16
    int2* erec = (int2*)(h + (size_t)N_NODES * DIM);              // 4.8 MB
    unsigned short* Hm16 = (unsigned short*)(erec + N_EDGES);     // 391*782*2 B
    int*  tot  = (int*)(Hm16 + (size_t)NJ * NB);                  // 782 ints
    int*  boff = tot + NB;                                        // 783 ints
    int*  done = boff + (NB + 1);                                 // 1 int
    size_t need = (size_t)((char*)(done + 1) - (char*)d_ws);

    if (ws_size >= need) {
        gemm_kernel<<<NJ, 512, 0, stream>>>(x, W, h, rows, Hm16, done);
        scanAB_kernel<<<13, 512, 0, stream>>>(Hm16, tot, boff, done);
        scatter_kernel<<<NJ, 512, 0, stream>>>(rows, cols, vals, Hm16, boff, erec);
        gather_kernel<<<NB, 512, 0, stream>>>(h, erec, boff, out);
    } else {
        // fallback: atomic scatter path (needs only h)
        gemm_kernel<<<NJ, 512, 0, stream>>>(x, W, h, nullptr, nullptr, nullptr);
        hipMemsetAsync(d_out, 0, (size_t)N_NODES * DIM * sizeof(float), stream);
        edge_kernel<<<(N_EDGES * 32) / 256, 256, 0, stream>>>(h, vals, rows, cols, out);
        relu_kernel<<<(N_NODES * DIM / 4) / 256, 256, 0, stream>>>(out);
    }
}

// Round 10
// 76.435 us; speedup vs baseline: 1.1366x; 1.1366x over previous
//
#include <hip/hip_runtime.h>

#define N_NODES 50000
#define N_EDGES 600000
#define DIM 128
#define NB 782                 // 64-node buckets (= gather blocks)
#define NJ 391                 // gemm/scatter blocks; 2 tiles or 1536 edges each
#define EPB 1536               // edges per partition block: 391*1536 = 600576
#define GCAP 2048              // gather LDS sort capacity (mean 767, sd 28)

typedef short bf16x8 __attribute__((ext_vector_type(8)));
typedef float f32x4 __attribute__((ext_vector_type(4)));

__device__ __forceinline__ float bf2f(unsigned short u) {
    union { unsigned int i; float f; } x; x.i = ((unsigned int)u) << 16; return x.f;
}
__device__ __forceinline__ unsigned short f2bf(float f) {
    union { float f; unsigned int i; } x; x.f = f;
    unsigned int r = x.i + 0x7FFFu + ((x.i >> 16) & 1u);   // RNE
    return (unsigned short)(r >> 16);
}

// ---------------- MFMA GEMM: 2 node-tiles/block sharing one W staging ----------------
__global__ __launch_bounds__(512) void gemm_kernel(const float* __restrict__ x,
                                                   const float* __restrict__ W,
                                                   unsigned short* __restrict__ h,
                                                   const int* __restrict__ rows,
                                                   unsigned short* __restrict__ Hm16,
                                                   int* __restrict__ done) {
    __shared__ unsigned char Wl[128 * 256];   // bf16[128 dims][128 k], swizzled
    __shared__ int cntL[NB];
    const int tid = threadIdx.x;

    if (Hm16) {
        for (int i = tid; i < NB; i += 512) cntL[i] = 0;
        if (blockIdx.x == 0 && tid == 0) *done = 0;    // reset last-block counter
    }

    // ---- stage W -> LDS bf16 (swizzled): 4096 float4 chunks, 8 per thread
#pragma unroll
    for (int i = 0; i < 8; ++i) {
        int c  = tid + i * 512;
        int od = c >> 5;
        int kg = c & 31;
        float4 w = *((const float4*)(W + od * DIM) + kg);
        unsigned int lo = (unsigned int)f2bf(w.x) | ((unsigned int)f2bf(w.y) << 16);
        unsigned int hi = (unsigned int)f2bf(w.z) | ((unsigned int)f2bf(w.w) << 16);
        int byte = od * 256 + ((kg * 8) ^ ((od & 7) << 4));
        *reinterpret_cast<uint2*>(Wl + byte) = make_uint2(lo, hi);
    }

    // ---- this wave's tile + node (node = lane&15, k-slot q = lane>>4)
    const int lane = tid & 63;
    const int w8   = tid >> 6;          // wave 0..7
    const int wv   = w8 & 3;            // wave-in-tile
    const int t    = blockIdx.x * 2 + (w8 >> 2);   // tile 0..781
    const int q    = lane >> 4;
    const int node = t * 64 + wv * 16 + (lane & 15);
    const int ncl  = node < N_NODES ? node : N_NODES - 1;

    bf16x8 xb[4];
#pragma unroll
    for (int s = 0; s < 4; ++s) {
        const float* xp = x + (size_t)ncl * DIM + s * 32 + q * 8;
        float4 x0 = *(const float4*)(xp);
        float4 x1 = *(const float4*)(xp + 4);
        bf16x8 v;
        v[0] = (short)f2bf(x0.x); v[1] = (short)f2bf(x0.y);
        v[2] = (short)f2bf(x0.z); v[3] = (short)f2bf(x0.w);
        v[4] = (short)f2bf(x1.x); v[5] = (short)f2bf(x1.y);
        v[6] = (short)f2bf(x1.z); v[7] = (short)f2bf(x1.w);
        xb[s] = v;
    }

    __syncthreads();   // cntL zeroed + W staged

    // ---- fused histogram: LDS atomics only (1536 edges/block)
    if (Hm16) {
        int ebase = blockIdx.x * EPB;
#pragma unroll
        for (int i = 0; i < 3; ++i) {
            int e = ebase + tid + i * 512;
            if (e < N_EDGES) atomicAdd(&cntL[rows[e] >> 6], 1);
        }
    }

    // ---- 8 dim-tiles x 4 k-steps of mfma_f32_16x16x32_bf16
#pragma unroll
    for (int dt = 0; dt < 8; ++dt) {
        f32x4 acc = {0.f, 0.f, 0.f, 0.f};
        const int od = dt * 16 + (lane & 15);
#pragma unroll
        for (int s = 0; s < 4; ++s) {
            int byte = od * 256 + ((s * 64 + q * 16) ^ ((od & 7) << 4));
            bf16x8 a = *reinterpret_cast<const bf16x8*>(Wl + byte);
            acc = __builtin_amdgcn_mfma_f32_16x16x32_bf16(a, xb[s], acc, 0, 0, 0);
        }
        if (node < N_NODES) {
            unsigned int lo = (unsigned int)f2bf(acc[0]) | ((unsigned int)f2bf(acc[1]) << 16);
            unsigned int hi = (unsigned int)f2bf(acc[2]) | ((unsigned int)f2bf(acc[3]) << 16);
            *reinterpret_cast<uint2*>(h + (size_t)node * DIM + dt * 16 + q * 4) = make_uint2(lo, hi);
        }
    }

    if (Hm16) {
        __syncthreads();
        unsigned short* Hrow = Hm16 + (size_t)blockIdx.x * NB;
        for (int i = tid; i < NB; i += 512) Hrow[i] = (unsigned short)cntL[i];
    }
}

// ---------------- scanAB: coalesced per-bucket scan along j + last-block scanB ----------------
__global__ __launch_bounds__(512) void scanAB_kernel(unsigned short* __restrict__ Hm16,
                                                     int* __restrict__ tot,
                                                     int* __restrict__ boff,
                                                     int* __restrict__ done) {
    __shared__ int part[8 * 64];
    __shared__ int lastFlag;
    int tid = threadIdx.x, g = blockIdx.x;
    int w = tid >> 6, lane = tid & 63;
    int bucket = g * 64 + lane;
    bool bv = bucket < NB;
    int j0 = w * 49;
    int j1 = j0 + 49; if (j1 > NJ) j1 = NJ;

    // pass 1: per-(wave,bucket) partial sums
    int ps = 0;
    if (bv) for (int j = j0; j < j1; ++j) ps += Hm16[(size_t)j * NB + bucket];
    part[w * 64 + lane] = ps;
    __syncthreads();
    int base = 0, total = 0;
#pragma unroll
    for (int ww = 0; ww < 8; ++ww) {
        int p = part[ww * 64 + lane];
        if (ww < w) base += p;
        total += p;
    }
    if (w == 0 && bv) tot[bucket] = total;

    // pass 2: write exclusive prefix back (u16)
    if (bv) {
        int carry = base;
        for (int j = j0; j < j1; ++j) {
            size_t idx = (size_t)j * NB + bucket;
            int v = Hm16[idx];
            Hm16[idx] = (unsigned short)carry;
            carry += v;
        }
    }
    __syncthreads();
    if (tid == 0) {
        __threadfence();
        int old = atomicAdd(done, 1);
        lastFlag = (old == (int)gridDim.x - 1) ? 1 : 0;
    }
    __syncthreads();
    if (lastFlag) {
        __threadfence();   // acquire other blocks' tot writes
        if (tid < 64) {
            int carry = 0;
            for (int ch = 0; ch < 13; ++ch) {
                int i = ch * 64 + tid;
                int v = (i < NB) ? tot[i] : 0;
                int incl = v;
#pragma unroll
                for (int d = 1; d < 64; d <<= 1) {
                    int t = __shfl_up(incl, d);
                    if (tid >= d) incl += t;
                }
                if (i < NB) boff[i] = carry + incl - v;
                carry += __shfl(incl, 63);
            }
            if (tid == 0) { boff[NB] = N_EDGES; *done = 0; }
        }
    }
}

// ---------------- scatter: deterministic bucket partition, LDS cursors ----------------
__global__ __launch_bounds__(512) void scatter_kernel(const int* __restrict__ rows,
                                                      const int* __restrict__ cols,
                                                      const float* __restrict__ vals,
                                                      const unsigned short* __restrict__ Hm16,
                                                      const int* __restrict__ boff,
                                                      int2* __restrict__ erec) {
    __shared__ int cl[NB];
    int tid = threadIdx.x, j = blockIdx.x;
    const unsigned short* Hrow = Hm16 + (size_t)j * NB;
    for (int i = tid; i < NB; i += 512) cl[i] = boff[i] + (int)Hrow[i];
    __syncthreads();
    int ebase = j * EPB;
#pragma unroll
    for (int i = 0; i < 3; ++i) {
        int e = ebase + tid + i * 512;
        if (e < N_EDGES) {
            int r = rows[e];
            int slot = atomicAdd(&cl[r >> 6], 1);
            int2 rec;
            rec.x = cols[e] | ((r & 63) << 16);
            rec.y = __float_as_int(vals[e]);
            erec[slot] = rec;
        }
    }
}

// ---------------- gather: LDS counting sort + FULL-WAVE per node, 4-deep unroll ----------------
// 512 threads, 8 waves, 8 nodes/wave (sequential). One full wave per node:
// lane owns dims {2*lane, 2*lane+1} (ushort2, perfectly coalesced 256B/load).
// Node segment = full degree (~12), so the 4-deep unrolled main loop executes
// ~2-3 times -> 4 independent loads in flight. No cross-lane combine needed.
__global__ __launch_bounds__(512) void gather_kernel(const unsigned short* __restrict__ h,
                                                     const int2* __restrict__ erec,
                                                     const int* __restrict__ boff,
                                                     float* __restrict__ out) {
    __shared__ int2 srt[GCAP];            // 16 KB sorted records
    __shared__ int hist[64];
    __shared__ int cursor[64];
    __shared__ int starts[65];
    int tid = threadIdx.x, b = blockIdx.x;
    int beg = boff[b], end = boff[b + 1];
    int cnt = end - beg;
    int w = tid >> 6, lane = tid & 63;

    if (tid < 64) hist[tid] = 0;
    __syncthreads();

    if (cnt <= GCAP) {
        // ---- phase 1: stage to registers + 64-bin histogram
        int2 rec[4];
        int  rr[4];
#pragma unroll
        for (int k = 0; k < 4; ++k) {
            int i = tid + k * 512;
            if (i < cnt) {
                rec[k] = erec[beg + i];
                rr[k] = (rec[k].x >> 16) & 63;
                atomicAdd(&hist[rr[k]], 1);
            }
        }
        __syncthreads();
        // ---- phase 2: exclusive scan of the 64 bins (wave 0)
        if (tid < 64) {
            int v = hist[tid], incl = v;
#pragma unroll
            for (int d = 1; d < 64; d <<= 1) {
                int t = __shfl_up(incl, d);
                if (tid >= d) incl += t;
            }
            starts[tid] = incl - v;
            cursor[tid] = incl - v;
            if (tid == 63) starts[64] = incl;
        }
        __syncthreads();
        // ---- phase 3: place into sorted LDS order
#pragma unroll
        for (int k = 0; k < 4; ++k) {
            int i = tid + k * 512;
            if (i < cnt) {
                int p2 = atomicAdd(&cursor[rr[k]], 1);
                srt[p2] = rec[k];
            }
        }
        __syncthreads();
        // ---- phase 4: full wave per node, 4-deep unroll
        for (int t0 = 0; t0 < 8; ++t0) {
            int t = w * 8 + t0;
            int node = b * 64 + t;
            int s0 = starts[t], s1 = starts[t + 1];
            float ax = 0.f, ay = 0.f;
            int i = s0;
            for (; i + 4 <= s1; i += 4) {
                int2 r0 = srt[i], r1 = srt[i + 1], r2 = srt[i + 2], r3 = srt[i + 3];
                ushort2 h0 = *((const ushort2*)(h + (size_t)(r0.x & 0xFFFF) * DIM) + lane);
                ushort2 h1 = *((const ushort2*)(h + (size_t)(r1.x & 0xFFFF) * DIM) + lane);
                ushort2 h2 = *((const ushort2*)(h + (size_t)(r2.x & 0xFFFF) * DIM) + lane);
                ushort2 h3 = *((const ushort2*)(h + (size_t)(r3.x & 0xFFFF) * DIM) + lane);
                float v0 = __int_as_float(r0.y), v1 = __int_as_float(r1.y);
                float v2 = __int_as_float(r2.y), v3 = __int_as_float(r3.y);
                ax += v0 * bf2f(h0.x) + v1 * bf2f(h1.x) + v2 * bf2f(h2.x) + v3 * bf2f(h3.x);
                ay += v0 * bf2f(h0.y) + v1 * bf2f(h1.y) + v2 * bf2f(h2.y) + v3 * bf2f(h3.y);
            }
            for (; i < s1; ++i) {
                int2 r0 = srt[i];
                ushort2 h0 = *((const ushort2*)(h + (size_t)(r0.x & 0xFFFF) * DIM) + lane);
                float v0 = __int_as_float(r0.y);
                ax += v0 * bf2f(h0.x);
                ay += v0 * bf2f(h0.y);
            }
            if (node < N_NODES) {
                float2 o;
                o.x = fmaxf(ax, 0.f);
                o.y = fmaxf(ay, 0.f);
                *reinterpret_cast<float2*>(&out[(size_t)node * DIM + lane * 2]) = o;
            }
        }
    } else {
        // ---- oversize-bucket fallback (statistically unreachable, kept for correctness)
        for (int t0 = 0; t0 < 8; ++t0) {
            int t = w * 8 + t0;
            int node = b * 64 + t;
            float ax = 0.f, ay = 0.f;
            for (int i = 0; i < cnt; ++i) {
                int2 r = erec[beg + i];
                if (((r.x >> 16) & 63) == t) {
                    ushort2 hv = *((const ushort2*)(h + (size_t)(r.x & 0xFFFF) * DIM) + lane);
                    float v = __int_as_float(r.y);
                    ax += v * bf2f(hv.x);
                    ay += v * bf2f(hv.y);
                }
            }
            if (node < N_NODES) {
                float2 o;
                o.x = fmaxf(ax, 0.f);
                o.y = fmaxf(ay, 0.f);
                *reinterpret_cast<float2*>(&out[(size_t)node * DIM + lane * 2]) = o;
            }
        }
    }
}

// ---------------- fallback: atomic scatter over bf16 h ----------------
__global__ __launch_bounds__(256) void edge_kernel(const unsigned short* __restrict__ h,
                                                   const float* __restrict__ vals,
                                                   const int* __restrict__ rows,
                                                   const int* __restrict__ cols,
                                                   float* __restrict__ out) {
    long long gid = (long long)blockIdx.x * 256 + threadIdx.x;
    int e    = (int)(gid >> 5);
    int lane = (int)(gid & 31);
    if (e >= N_EDGES) return;
    int r = rows[e];
    int c = cols[e];
    float v = vals[e];
    ushort4 hv = *((const ushort4*)(h + (size_t)c * DIM) + lane);
    float* op = &out[(size_t)r * DIM + lane * 4];
    atomicAdd(op + 0, v * bf2f(hv.x));
    atomicAdd(op + 1, v * bf2f(hv.y));
    atomicAdd(op + 2, v * bf2f(hv.z));
    atomicAdd(op + 3, v * bf2f(hv.w));
}

__global__ __launch_bounds__(256) void relu_kernel(float* __restrict__ out) {
    int i = blockIdx.x * 256 + threadIdx.x;
    float4* p = reinterpret_cast<float4*>(out) + i;
    float4 v = *p;
    v.x = fmaxf(v.x, 0.f);
    v.y = fmaxf(v.y, 0.f);
    v.z = fmaxf(v.z, 0.f);
    v.w = fmaxf(v.w, 0.f);
    *p = v;
}

extern "C" void kernel_launch(void* const* d_in, const int* in_sizes, int n_in,
                              void* d_out, int out_size, void* d_ws, size_t ws_size,
                              hipStream_t stream) {
    const float* x    = (const float*)d_in[0];
    const float* W    = (const float*)d_in[1];
    const float* vals = (const float*)d_in[2];
    const int*   rows = (const int*)d_in[3];
    const int*   cols = (const int*)d_in[4];
    float* out = (float*)d_out;

    // ---- workspace layout ----
    unsigned short* h = (unsigned short*)d_ws;                    // 12.8 MB bf16
    int2* erec = (int2*)(h + (size_t)N_NODES * DIM);              // 4.8 MB
    unsigned short* Hm16 = (unsigned short*)(erec + N_EDGES);     // 391*782*2 B
    int*  tot  = (int*)(Hm16 + (size_t)NJ * NB);                  // 782 ints
    int*  boff = tot + NB;                                        // 783 ints
    int*  done = boff + (NB + 1);                                 // 1 int
    size_t need = (size_t)((char*)(done + 1) - (char*)d_ws);

    if (ws_size >= need) {
        gemm_kernel<<<NJ, 512, 0, stream>>>(x, W, h, rows, Hm16, done);
        scanAB_kernel<<<13, 512, 0, stream>>>(Hm16, tot, boff, done);
        scatter_kernel<<<NJ, 512, 0, stream>>>(rows, cols, vals, Hm16, boff, erec);
        gather_kernel<<<NB, 512, 0, stream>>>(h, erec, boff, out);
    } else {
        // fallback: atomic scatter path (needs only h)
        gemm_kernel<<<NJ, 512, 0, stream>>>(x, W, h, nullptr, nullptr, nullptr);
        hipMemsetAsync(d_out, 0, (size_t)N_NODES * DIM * sizeof(float), stream);
        edge_kernel<<<(N_EDGES * 32) / 256, 256, 0, stream>>>(h, vals, rows, cols, out);
        relu_kernel<<<(N_NODES * DIM / 4) / 256, 256, 0, stream>>>(out);
    }
}